// Round 5
// baseline (204.414 us; speedup 1.0000x reference)
//
#include <hip/hip_runtime.h>

#define DEV_INLINE __device__ __forceinline__

// Native clang vector type — required by __builtin_nontemporal_store.
typedef float vfloat4 __attribute__((ext_vector_type(4)));

// softplus(v) = max(v,0) + ln2 * log2(1 + 2^(-|v|*log2e))
DEV_INLINE float softplus_f(float v) {
#if __has_builtin(__builtin_amdgcn_logf) && __has_builtin(__builtin_amdgcn_exp2f)
    float e = __builtin_amdgcn_exp2f(fabsf(v) * -1.44269504f);
    float l = __builtin_amdgcn_logf(1.0f + e);            // v_log_f32 = log2
    return fmaf(0.69314718f, l, fmaxf(v, 0.0f));
#else
    return fmaxf(v, 0.0f) + __logf(1.0f + __expf(-fabsf(v)));
#endif
}

// R5: 4 rows per thread, computed CONCURRENTLY (R2/R4 were 1 row/thread and
// neutral to barrier/store/softplus tweaks -> diagnosis: latency-bound on the
// single dependent MLP chain per thread). 4 independent chains give 4x
// in-thread ILP over transcendental + scalar-weight-load latency, and all
// 12 x-loads issue up-front (vmcnt overlap). Block = 256 thr = 4 waves
// covering 1024 rows as 4 sub-batches of 256; each wave stages sub-batch s
// through its private 9 KB LDS region (reused x4, in-wave DS ordering + fence)
// then streams 1 KiB/instruction coalesced nt stores.
// __launch_bounds__(256,4): keep VGPR <= 128 so occupancy stays LDS-limited
// (36 KB -> 4 blocks/CU = 16 waves/CU).
__global__ __launch_bounds__(256, 4) void pb_kernel(
    const float* __restrict__ x,
    const float* __restrict__ W_in, const float* __restrict__ b_in,
    const float* __restrict__ W1,   const float* __restrict__ b1,
    const float* __restrict__ W2,   const float* __restrict__ b2,
    const float* __restrict__ W3,   const float* __restrict__ b3,
    const float* __restrict__ W4,   const float* __restrict__ b4,
    const float* __restrict__ W_out,const float* __restrict__ b_out,
    float* __restrict__ out, int n_rows)
{
    __shared__ vfloat4 sbuf[4][64 * 9];   // 36 KB: per-wave 9 KB regions

    const int tid  = threadIdx.x;
    const int wave = tid >> 6;
    const int lane = tid & 63;
    const long long blockbase = (long long)blockIdx.x * 1024;  // grid exact

    // ---- load 4 rows of x up-front (12 independent float2 loads) ----
    float xin[4][6];
    #pragma unroll
    for (int s = 0; s < 4; ++s) {
        const long long row = blockbase + s * 256 + tid;
        const float2* xv = (const float2*)(x + row * 6);
        float2 p0 = xv[0], p1 = xv[1], p2 = xv[2];
        xin[s][0] = p0.x; xin[s][1] = p0.y;
        xin[s][2] = p1.x; xin[s][3] = p1.y;
        xin[s][4] = p2.x; xin[s][5] = p2.y;
    }

    // ---- input layer 6 -> 8, 4 rows interleaved ----
    float y[4][8];
    #pragma unroll
    for (int o = 0; o < 8; ++o) {
        #pragma unroll
        for (int s = 0; s < 4; ++s) {
            float acc = b_in[o];
            #pragma unroll
            for (int i = 0; i < 6; ++i)
                acc = fmaf(W_in[o * 6 + i], xin[s][i], acc);
            y[s][o] = softplus_f(acc);
        }
    }

    // ---- 4 hidden layers 8 -> 8, 4 rows interleaved ----
    const float* Ws[4] = { W1, W2, W3, W4 };
    const float* bs[4] = { b1, b2, b3, b4 };
    #pragma unroll
    for (int l = 0; l < 4; ++l) {
        const float* __restrict__ W = Ws[l];
        const float* __restrict__ b = bs[l];
        float t[4][8];
        #pragma unroll
        for (int o = 0; o < 8; ++o) {
            #pragma unroll
            for (int s = 0; s < 4; ++s) {
                float acc = b[o];
                #pragma unroll
                for (int i = 0; i < 8; ++i)
                    acc = fmaf(W[o * 8 + i], y[s][i], acc);
                t[s][o] = softplus_f(acc);
            }
        }
        #pragma unroll
        for (int s = 0; s < 4; ++s)
            #pragma unroll
            for (int o = 0; o < 8; ++o)
                y[s][o] = t[s][o];
    }

    // ---- per sub-batch: output layer, expand, stage, coalesced store ----
    vfloat4* ws = sbuf[wave];
    #pragma unroll
    for (int s = 0; s < 4; ++s) {
        float u[15];
        #pragma unroll
        for (int o = 0; o < 15; ++o) {
            float acc = b_out[o];
            #pragma unroll
            for (int i = 0; i < 8; ++i)
                acc = fmaf(W_out[o * 8 + i], y[s][i], acc);
            u[o] = acc;
        }

        float L[36];
        #pragma unroll
        for (int i = 0; i < 36; ++i) L[i] = 0.0f;
        {
            int k = 0;
            #pragma unroll
            for (int i = 0; i < 6; ++i) {
                #pragma unroll
                for (int j = i + 1; j < 6; ++j) {
                    L[i * 6 + j] = u[k];
                    L[j * 6 + i] = -u[k];
                    ++k;
                }
            }
        }

        // stage: lane l, chunk m -> bank group (l+m)%8, wave-uniform spread
        #pragma unroll
        for (int m = 0; m < 9; ++m) {
            vfloat4 v = { L[4 * m + 0], L[4 * m + 1], L[4 * m + 2], L[4 * m + 3] };
            ws[lane * 9 + m] = v;
        }

        // drain this wave's DS writes before readback (in-wave RAW fence)
        asm volatile("s_waitcnt lgkmcnt(0)" ::: "memory");

        // 9 KB contiguous per wave; 1 KiB per store instruction; nontemporal
        vfloat4* dst = (vfloat4*)out
                     + (blockbase + s * 256 + wave * 64) * 9;
        #pragma unroll
        for (int q = 0; q < 9; ++q) {
            vfloat4 v = ws[q * 64 + lane];
            __builtin_nontemporal_store(v, &dst[q * 64 + lane]);
        }
        // next iteration's ds_writes are WAR-safe: same-wave DS ops process
        // in order, and the compiler can't reorder aliasing LDS write/read.
    }
}

extern "C" void kernel_launch(void* const* d_in, const int* in_sizes, int n_in,
                              void* d_out, int out_size, void* d_ws, size_t ws_size,
                              hipStream_t stream) {
    const float* x     = (const float*)d_in[0];
    const float* W_in  = (const float*)d_in[1];
    const float* b_in  = (const float*)d_in[2];
    const float* W1    = (const float*)d_in[3];
    const float* b1    = (const float*)d_in[4];
    const float* W2    = (const float*)d_in[5];
    const float* b2    = (const float*)d_in[6];
    const float* W3    = (const float*)d_in[7];
    const float* b3    = (const float*)d_in[8];
    const float* W4    = (const float*)d_in[9];
    const float* b4    = (const float*)d_in[10];
    const float* W_out = (const float*)d_in[11];
    const float* b_out = (const float*)d_in[12];
    float* out = (float*)d_out;

    const int n_rows = in_sizes[0] / 6;      // 1,048,576 = 1024 * 1024
    const int rows_per_block = 1024;
    const int grid = (n_rows + rows_per_block - 1) / rows_per_block;

    hipLaunchKernelGGL(pb_kernel, dim3(grid), dim3(256), 0, stream,
                       x, W_in, b_in, W1, b1, W2, b2, W3, b3, W4, b4,
                       W_out, b_out, out, n_rows);
}

// Round 6
// 197.617 us; speedup vs baseline: 1.0344x; 1.0344x over previous
//
#include <hip/hip_runtime.h>

#define DEV_INLINE __device__ __forceinline__

// Native clang vector type — required by __builtin_nontemporal_store.
typedef float vfloat4 __attribute__((ext_vector_type(4)));

// softplus(v) = max(v,0) + ln2 * log2(1 + 2^(-|v|*log2e))
DEV_INLINE float softplus_f(float v) {
#if __has_builtin(__builtin_amdgcn_logf) && __has_builtin(__builtin_amdgcn_exp2f)
    float e = __builtin_amdgcn_exp2f(fabsf(v) * -1.44269504f);
    float l = __builtin_amdgcn_logf(1.0f + e);            // v_log_f32 = log2
    return fmaf(0.69314718f, l, fmaxf(v, 0.0f));
#else
    return fmaxf(v, 0.0f) + __logf(1.0f + __expf(-fabsf(v)));
#endif
}

// LDS weight layout (floats):
//   [0)    W_in 48 | [48) b_in 8 | [56) W1 64 | [120) b1 8 | [128) W2 64
//   [192)  b2 8    | [200) W3 64 | [264) b3 8 | [272) W4 64 | [336) b4 8
//   [344)  W_out 120 | [464) b_out 15  -> 479 floats total
#define OFF_WIN  0
#define OFF_BIN  48
#define OFF_W1   56
#define OFF_B1   120
#define OFF_W2   128
#define OFF_B2   192
#define OFF_W3   200
#define OFF_B3   264
#define OFF_W4   272
#define OFF_B4   336
#define OFF_WOUT 344
#define OFF_BOUT 464
#define N_WF     479

// R6: R2 structure (1 row/thread, per-wave LDS output staging, coalesced nt
// stores) + ALL weights staged in LDS. Theory: waves were ~90% stalled on
// serialized s_load chains (479 weight dwords >> 112 SGPRs -> repeated
// scalar-cache round-trips, shared by all 16 waves/CU). LDS weight reads are
// uniform-address ds_read at immediate offsets: broadcast, conflict-free,
// latency-pipelined, and leave the scalar pipe empty.
__global__ __launch_bounds__(256) void pb_kernel(
    const float* __restrict__ x,
    const float* __restrict__ W_in, const float* __restrict__ b_in,
    const float* __restrict__ W1,   const float* __restrict__ b1,
    const float* __restrict__ W2,   const float* __restrict__ b2,
    const float* __restrict__ W3,   const float* __restrict__ b3,
    const float* __restrict__ W4,   const float* __restrict__ b4,
    const float* __restrict__ W_out,const float* __restrict__ b_out,
    float* __restrict__ out, int n_rows)
{
    __shared__ vfloat4 sbuf[4][64 * 9];   // 36 KB output staging (per-wave 9 KB)
    __shared__ float   wf[480];           // 1.9 KB weights/biases

    const int tid  = threadIdx.x;
    const int wave = tid >> 6;
    const int lane = tid & 63;
    const int row_raw = blockIdx.x * 256 + tid;
    const int row = row_raw < n_rows ? row_raw : n_rows - 1;   // grid is exact

    // ---- issue x loads FIRST so HBM latency overlaps weight staging ----
    const float2* xv = (const float2*)(x + (size_t)row * 6);
    float2 p0 = xv[0], p1 = xv[1], p2 = xv[2];

    // ---- cooperative weight copy: thread t handles j = t and t+256 ----
    #pragma unroll
    for (int rep = 0; rep < 2; ++rep) {
        int j = tid + rep * 256;
        if (j < N_WF) {
            float v;
            if      (j < OFF_BIN)  v = W_in [j - OFF_WIN ];
            else if (j < OFF_W1)   v = b_in [j - OFF_BIN ];
            else if (j < OFF_B1)   v = W1   [j - OFF_W1  ];
            else if (j < OFF_W2)   v = b1   [j - OFF_B1  ];
            else if (j < OFF_B2)   v = W2   [j - OFF_W2  ];
            else if (j < OFF_W3)   v = b2   [j - OFF_B2  ];
            else if (j < OFF_B3)   v = W3   [j - OFF_W3  ];
            else if (j < OFF_W4)   v = b3   [j - OFF_B3  ];
            else if (j < OFF_B4)   v = W4   [j - OFF_W4  ];
            else if (j < OFF_WOUT) v = b4   [j - OFF_B4  ];
            else if (j < OFF_BOUT) v = W_out[j - OFF_WOUT];
            else                   v = b_out[j - OFF_BOUT];
            wf[j] = v;
        }
    }
    __syncthreads();

    const float xin[6] = { p0.x, p0.y, p1.x, p1.y, p2.x, p2.y };

    // ---- input layer 6 -> 8 ----
    float y[8];
    #pragma unroll
    for (int o = 0; o < 8; ++o) {
        float acc = wf[OFF_BIN + o];
        #pragma unroll
        for (int i = 0; i < 6; ++i)
            acc = fmaf(wf[OFF_WIN + o * 6 + i], xin[i], acc);
        y[o] = softplus_f(acc);
    }

    // ---- 4 hidden layers 8 -> 8 (weights at compile-time LDS offsets) ----
    const int wofs[4] = { OFF_W1, OFF_W2, OFF_W3, OFF_W4 };
    const int bofs[4] = { OFF_B1, OFF_B2, OFF_B3, OFF_B4 };
    #pragma unroll
    for (int l = 0; l < 4; ++l) {
        const int wo = wofs[l], bo = bofs[l];
        float t[8];
        #pragma unroll
        for (int o = 0; o < 8; ++o) {
            float acc = wf[bo + o];
            #pragma unroll
            for (int i = 0; i < 8; ++i)
                acc = fmaf(wf[wo + o * 8 + i], y[i], acc);
            t[o] = softplus_f(acc);
        }
        #pragma unroll
        for (int o = 0; o < 8; ++o) y[o] = t[o];
    }

    // ---- output layer 8 -> 15 ----
    float u[15];
    #pragma unroll
    for (int o = 0; o < 15; ++o) {
        float acc = wf[OFF_BOUT + o];
        #pragma unroll
        for (int i = 0; i < 8; ++i)
            acc = fmaf(wf[OFF_WOUT + o * 8 + i], y[i], acc);
        u[o] = acc;
    }

    // ---- assemble antisymmetric 6x6 ----
    float L[36];
    #pragma unroll
    for (int i = 0; i < 36; ++i) L[i] = 0.0f;
    {
        int k = 0;
        #pragma unroll
        for (int i = 0; i < 6; ++i) {
            #pragma unroll
            for (int j = i + 1; j < 6; ++j) {
                L[i * 6 + j] = u[k];
                L[j * 6 + i] = -u[k];
                ++k;
            }
        }
    }

    // ---- stage to this wave's LDS region (bank-uniform, see R2) ----
    vfloat4* ws = sbuf[wave];
    #pragma unroll
    for (int m = 0; m < 9; ++m) {
        vfloat4 v = { L[4 * m + 0], L[4 * m + 1], L[4 * m + 2], L[4 * m + 3] };
        ws[lane * 9 + m] = v;
    }

    // in-wave RAW fence for the staging writes
    asm volatile("s_waitcnt lgkmcnt(0)" ::: "memory");

    // ---- wave-coalesced streaming store: 1 KiB per instruction ----
    vfloat4* dst = (vfloat4*)out + (size_t)blockIdx.x * (256 * 9) + wave * (64 * 9);
    #pragma unroll
    for (int q = 0; q < 9; ++q) {
        vfloat4 v = ws[q * 64 + lane];
        __builtin_nontemporal_store(v, &dst[q * 64 + lane]);
    }
}

extern "C" void kernel_launch(void* const* d_in, const int* in_sizes, int n_in,
                              void* d_out, int out_size, void* d_ws, size_t ws_size,
                              hipStream_t stream) {
    const float* x     = (const float*)d_in[0];
    const float* W_in  = (const float*)d_in[1];
    const float* b_in  = (const float*)d_in[2];
    const float* W1    = (const float*)d_in[3];
    const float* b1    = (const float*)d_in[4];
    const float* W2    = (const float*)d_in[5];
    const float* b2    = (const float*)d_in[6];
    const float* W3    = (const float*)d_in[7];
    const float* b3    = (const float*)d_in[8];
    const float* W4    = (const float*)d_in[9];
    const float* b4    = (const float*)d_in[10];
    const float* W_out = (const float*)d_in[11];
    const float* b_out = (const float*)d_in[12];
    float* out = (float*)d_out;

    const int n_rows = in_sizes[0] / 6;           // B*T = 1,048,576 (mult of 256)
    const int block = 256;
    const int grid = (n_rows + block - 1) / block;

    hipLaunchKernelGGL(pb_kernel, dim3(grid), dim3(block), 0, stream,
                       x, W_in, b_in, W1, b1, W2, b2, W3, b3, W4, b4,
                       W_out, b_out, out, n_rows);
}